// Round 3
// baseline (2364.758 us; speedup 1.0000x reference)
//
#include <hip/hip_runtime.h>
#include <hip/hip_bf16.h>
#include <stdint.h>
#include <stddef.h>

typedef __bf16 bf16;
typedef bf16  bf16x4 __attribute__((ext_vector_type(4)));
typedef bf16  bf16x8 __attribute__((ext_vector_type(8)));
typedef float f32x4  __attribute__((ext_vector_type(4)));

// ---------------------------------------------------------------------------
// async global->LDS, 16B per lane. LDS dest is wave-uniform base + lane*16.
// ---------------------------------------------------------------------------
__device__ __forceinline__ void async_copy16(bf16* lds, const bf16* g) {
    __builtin_amdgcn_global_load_lds(
        (const __attribute__((address_space(1))) void*)g,
        (__attribute__((address_space(3))) void*)lds,
        16, 0, 0);
}

__device__ __forceinline__ void bar() { __builtin_amdgcn_s_barrier(); }
#define SFENCE() __builtin_amdgcn_sched_barrier(0)
#define WAIT_LGKM0() do { asm volatile("s_waitcnt lgkmcnt(0)"); SFENCE(); } while (0)
#define WAIT_VM6()   do { asm volatile("s_waitcnt vmcnt(6)");   SFENCE(); } while (0)
#define WAIT_VM0()   do { asm volatile("s_waitcnt vmcnt(0)");   SFENCE(); } while (0)

// ---------------------------------------------------------------------------
// cast fp32 -> bf16, 4 elems/thread (unchanged)
// ---------------------------------------------------------------------------
__global__ __launch_bounds__(256) void cast_f32_to_bf16(
        const float* __restrict__ in, bf16* __restrict__ out, int n4) {
    int i = blockIdx.x * blockDim.x + threadIdx.x;
    if (i >= n4) return;
    const float4 v = *(const float4*)(in + (size_t)i * 4);
    bf16x4 o;
    o[0] = (bf16)v.x; o[1] = (bf16)v.y; o[2] = (bf16)v.z; o[3] = (bf16)v.w;
    *(bf16x4*)(out + (size_t)i * 4) = o;
}

// ---------------------------------------------------------------------------
// W_eff[n][k] = (q[n][k] - 7.5) * scale[n][k/64] + sum_r A[k][r]*Bm[r][n]
// (unchanged)
// ---------------------------------------------------------------------------
__global__ __launch_bounds__(256) void dequant_lora(
        const int*   __restrict__ q,
        const float* __restrict__ scale,
        const float* __restrict__ A,
        const float* __restrict__ Bm,
        bf16* __restrict__ out,
        int N, int K) {
    const int tid = threadIdx.x;
    const int k0 = blockIdx.x * 64;
    const int n0 = blockIdx.y * 64;
    const int kk = k0 + (tid & 15) * 4;
    const int nb = n0 + (tid >> 4) * 4;

    f32x4 Ar[4][4];
    #pragma unroll
    for (int i = 0; i < 4; ++i)
        #pragma unroll
        for (int rq = 0; rq < 4; ++rq)
            Ar[i][rq] = *(const f32x4*)&A[(size_t)(kk + i) * 16 + rq * 4];
    f32x4 Br[16];
    #pragma unroll
    for (int r = 0; r < 16; ++r)
        Br[r] = *(const f32x4*)&Bm[(size_t)r * N + nb];

    const int scol = (unsigned)k0 >> 6;
    #pragma unroll
    for (int nn = 0; nn < 4; ++nn) {
        const int n = nb + nn;
        const int4 qv = *(const int4*)&q[(size_t)n * K + kk];
        const float s = scale[(size_t)n * (K >> 6) + scol];
        float l0 = 0.f, l1 = 0.f, l2 = 0.f, l3 = 0.f;
        #pragma unroll
        for (int r = 0; r < 16; ++r) {
            const float bv = Br[r][nn];
            l0 += Ar[0][r >> 2][r & 3] * bv;
            l1 += Ar[1][r >> 2][r & 3] * bv;
            l2 += Ar[2][r >> 2][r & 3] * bv;
            l3 += Ar[3][r >> 2][r & 3] * bv;
        }
        bf16x4 o;
        o[0] = (bf16)(((float)qv.x - 7.5f) * s + l0);
        o[1] = (bf16)(((float)qv.y - 7.5f) * s + l1);
        o[2] = (bf16)(((float)qv.z - 7.5f) * s + l2);
        o[3] = (bf16)(((float)qv.w - 7.5f) * s + l3);
        *(bf16x4*)&out[(size_t)n * K + kk] = o;
    }
}

// ---------------------------------------------------------------------------
// gemm_bt256 v7: 256x256 tile, BK=64, 8 waves, 8-phase, counted vmcnt.
//
// Changes vs v6 (both attack the same serialization, see round-2 notes):
//  (1) LDS split into 4 DISTINCT __shared__ arrays (As0/As1/Bs0/Bs1) and the
//      K-loop unrolled x2 so the double-buffer index is compile-time. With a
//      runtime index, alias analysis could not prove ds_reads disjoint from
//      pending global_load_lds DMAs, so SIInsertWaitcnts emitted a
//      vmcnt(0)-equivalent before every phase-1 read burst (why v6's barrier
//      edits were neutral: the drain was attached to the READS).
//  (2) Read-ahead, 8 ds_read_b128 per phase (was 16/0/8/0), each issued one
//      phase before its MFMA consumes it; NO explicit lgkmcnt(0) before MFMA
//      (compiler emits precise counted waits for plain LDS loads). One
//      lgkmcnt(0) at p1-end orders fb reads before p2's B-stage overwrite.
//
// Schedule per K-tile t (cur = dbuf t&1 arrays, nxt = other):
//  p1: read fb[0..3] (cur B) ; stage A-hi(t+1)->nxt | bar | MFMA Q0
//      (fan[t&1] x fb01) ; lgkm0 | bar
//  p2: read faB (cur A rows 64-127) ; stage B-lo(t+2)->cur | bar | MFMA Q1
//      (fan x fb23) | bar
//  p3: stage B-hi(t+2)->cur | bar | MFMA Q2 (faB x fb23) | bar
//  p4: stage A-lo(t+2)->cur ; vmcnt(6) | bar | read fan[(t+1)&1] from nxt
//      (A rows 0-63, valid: A-hi(t+1) retired by the vmcnt) ; MFMA Q3
//      (faB x fb01) | bar
// vmcnt(6): queue at p4 = {A-hi(t+1), B-lo(t+2), B-hi(t+2), A-lo(t+2)} x2
// loads = 8 -> retires A-hi(t+1) => ALL of tile t+1 resident; 6 stay in
// flight ACROSS barriers. Tail drains vmcnt(0).
// ---------------------------------------------------------------------------
template <bool RELU, typename OUT_T>
__global__ __launch_bounds__(512, 2) void gemm_bt256(
        const bf16* __restrict__ A, const bf16* __restrict__ B,
        const float* __restrict__ bias, OUT_T* __restrict__ C,
        int M, int N, int K) {
    __shared__ __attribute__((aligned(16))) bf16 As0[2][8192];
    __shared__ __attribute__((aligned(16))) bf16 As1[2][8192];
    __shared__ __attribute__((aligned(16))) bf16 Bs0[2][8192];
    __shared__ __attribute__((aligned(16))) bf16 Bs1[2][8192];

    const int tid  = threadIdx.x;
    const int wave = tid >> 6;
    const int lane = tid & 63;
    const int wm   = wave >> 2;     // 0..1 : row half of the 256-tile
    const int wn   = wave & 3;      // 0..3 : 64-col slice
    const int bn   = blockIdx.x;
    const int bm   = blockIdx.y;

    // staging: thread covers 16B-granule tid (rows 0..63) and tid+512
    // (rows 64..127) of each [128][64] half-tile; source col granule
    // pre-swizzled with the same involution the reads apply.
    const int srow = tid >> 3;
    const int scol = ((tid & 7) ^ (srow & 7)) * 8;   // elems
    const bf16* gA = A + ((size_t)(bm * 256) + srow) * K + scol;
    const bf16* gB = B + ((size_t)(bn * 256) + srow) * K + scol;

    auto stage2 = [&](bf16* halfBase, const bf16* g) {
        bf16* l = halfBase + wave * 512;             // wave-uniform dest
        async_copy16(l, g);
        async_copy16(l + 4096, g + (size_t)64 * K);  // rows +64
    };

    const int fr  = lane & 15;
    const int kq  = lane >> 4;
    const int cg0 = ((kq    ) ^ (fr & 7)) * 8;
    const int cg1 = ((kq + 4) ^ (fr & 7)) * 8;
    const int ra  = fr * 64;
    const int rb  = (wn & 1) * 4096 + fr * 64;       // 64-col offset in B half

    f32x4 acc[8][4];
    #pragma unroll
    for (int i = 0; i < 8; ++i)
        #pragma unroll
        for (int j = 0; j < 4; ++j) {
            f32x4 z = {0.f, 0.f, 0.f, 0.f};
            acc[i][j] = z;
        }

    // prologue: 7 half-tiles; first 4 = all of tile 0 (dbuf 0 arrays).
    stage2(&Bs0[0][0], gB);
    stage2(&Bs0[1][0], gB + (size_t)128 * K);
    stage2(&As0[0][0], gA);
    stage2(&As0[1][0], gA + (size_t)128 * K);
    stage2(&Bs1[0][0], gB + 64);
    stage2(&Bs1[1][0], gB + (size_t)128 * K + 64);
    stage2(&As1[0][0], gA + 64);
    WAIT_VM6();                      // 14 issued, retire oldest 8 = tile 0
    bar();

    const int NT = K >> 6;
    bf16x8 fan[2][4][2];             // A rows 0-63 fragment, banked by t&1
    bf16x8 faB[4][2];                // A rows 64-127 fragment (cur tile)
    bf16x8 fb[4][2];                 // B fragments (cur tile)

    // prologue reads: fan[0] for tile 0 (equivalent of t=-1.p4 read-ahead)
    {
        const bf16* aH = &As0[wm][0];
        #pragma unroll
        for (int i = 0; i < 4; ++i) {
            fan[0][i][0] = *(const bf16x8*)(aH + i * 1024 + ra + cg0);
            fan[0][i][1] = *(const bf16x8*)(aH + i * 1024 + ra + cg1);
        }
    }

    for (int t0 = 0; t0 < NT; t0 += 2) {
        #pragma unroll
        for (int u = 0; u < 2; ++u) {
            const int t = t0 + u;
            bf16 (*AsC)[8192] = u ? As1 : As0;   // cur dbuf (t&1==u)
            bf16 (*AsN)[8192] = u ? As0 : As1;   // next dbuf
            bf16 (*BsC)[8192] = u ? Bs1 : Bs0;
            const bf16* aC = &AsC[wm][0];
            const bf16* bC = &BsC[wn >> 1][0];
            const bf16* aN = &AsN[wm][0];

            // ---- phase 1: read fb, stage A-hi(t+1) | MFMA Q0 ------------
            #pragma unroll
            for (int j = 0; j < 4; ++j) {
                fb[j][0] = *(const bf16x8*)(bC + rb + j * 1024 + cg0);
                fb[j][1] = *(const bf16x8*)(bC + rb + j * 1024 + cg1);
            }
            if (t + 1 < NT)
                stage2(&AsN[1][0], gA + (size_t)128 * K + (size_t)(t + 1) * 64);
            bar();
            __builtin_amdgcn_s_setprio(1);
            #pragma unroll
            for (int ks = 0; ks < 2; ++ks)
                #pragma unroll
                for (int i = 0; i < 4; ++i)
                    #pragma unroll
                    for (int j = 0; j < 2; ++j)
                        acc[i][j] = __builtin_amdgcn_mfma_f32_16x16x32_bf16(
                            fan[u][i][ks], fb[j][ks], acc[i][j], 0, 0, 0);
            __builtin_amdgcn_s_setprio(0);
            WAIT_LGKM0();   // fb fully drained before p2 overwrites B region
            bar();

            // ---- phase 2: read faB, stage B-lo(t+2) | MFMA Q1 -----------
            #pragma unroll
            for (int i = 0; i < 4; ++i) {
                faB[i][0] = *(const bf16x8*)(aC + (i + 4) * 1024 + ra + cg0);
                faB[i][1] = *(const bf16x8*)(aC + (i + 4) * 1024 + ra + cg1);
            }
            if (t + 2 < NT)
                stage2(&BsC[0][0], gB + (size_t)(t + 2) * 64);
            bar();
            __builtin_amdgcn_s_setprio(1);
            #pragma unroll
            for (int ks = 0; ks < 2; ++ks)
                #pragma unroll
                for (int i = 0; i < 4; ++i)
                    #pragma unroll
                    for (int j = 2; j < 4; ++j)
                        acc[i][j] = __builtin_amdgcn_mfma_f32_16x16x32_bf16(
                            fan[u][i][ks], fb[j][ks], acc[i][j], 0, 0, 0);
            __builtin_amdgcn_s_setprio(0);
            bar();

            // ---- phase 3: stage B-hi(t+2) | MFMA Q2 ---------------------
            if (t + 2 < NT)
                stage2(&BsC[1][0], gB + (size_t)128 * K + (size_t)(t + 2) * 64);
            bar();
            __builtin_amdgcn_s_setprio(1);
            #pragma unroll
            for (int ks = 0; ks < 2; ++ks)
                #pragma unroll
                for (int i = 0; i < 4; ++i)
                    #pragma unroll
                    for (int j = 2; j < 4; ++j)
                        acc[i + 4][j] = __builtin_amdgcn_mfma_f32_16x16x32_bf16(
                            faB[i][ks], fb[j][ks], acc[i + 4][j], 0, 0, 0);
            __builtin_amdgcn_s_setprio(0);
            bar();

            // ---- phase 4: stage A-lo(t+2), vmcnt | read fan' ; MFMA Q3 --
            if (t + 2 < NT) {
                stage2(&AsC[0][0], gA + (size_t)(t + 2) * 64);
                WAIT_VM6();          // retires A-hi(t+1): tile t+1 resident
            } else {
                WAIT_VM0();          // tail drain
            }
            bar();
            if (t + 1 < NT) {
                #pragma unroll
                for (int i = 0; i < 4; ++i) {
                    fan[u ^ 1][i][0] = *(const bf16x8*)(aN + i * 1024 + ra + cg0);
                    fan[u ^ 1][i][1] = *(const bf16x8*)(aN + i * 1024 + ra + cg1);
                }
            }
            __builtin_amdgcn_s_setprio(1);
            #pragma unroll
            for (int ks = 0; ks < 2; ++ks)
                #pragma unroll
                for (int i = 0; i < 4; ++i)
                    #pragma unroll
                    for (int j = 0; j < 2; ++j)
                        acc[i + 4][j] = __builtin_amdgcn_mfma_f32_16x16x32_bf16(
                            faB[i][ks], fb[j][ks], acc[i + 4][j], 0, 0, 0);
            __builtin_amdgcn_s_setprio(0);
            bar();
        }
    }

    // epilogue: C/D layout col = lane&15, row = (lane>>4)*4 + reg (verified)
    const int er = bm * 256 + wm * 128 + (lane >> 4) * 4;
    const int ec = bn * 256 + wn * 64 + fr;
    #pragma unroll
    for (int j = 0; j < 4; ++j) {
        const int col = ec + j * 16;
        const float bv = bias[col];
        #pragma unroll
        for (int i = 0; i < 8; ++i) {
            #pragma unroll
            for (int r = 0; r < 4; ++r) {
                const int row = er + i * 16 + r;
                float v = acc[i][j][r] + bv;
                if (RELU) v = v > 0.f ? v : 0.f;
                C[(size_t)row * N + col] = (OUT_T)v;
            }
        }
    }
}

// ---------------------------------------------------------------------------
extern "C" void kernel_launch(void* const* d_in, const int* in_sizes, int n_in,
                              void* d_out, int out_size, void* d_ws, size_t ws_size,
                              hipStream_t stream) {
    const float* x1           = (const float*)d_in[0];
    const int*   w_up_q       = (const int*)  d_in[1];
    const float* w_up_scale   = (const float*)d_in[2];
    const float* b_up         = (const float*)d_in[3];
    const float* w_up_lora_a  = (const float*)d_in[4];
    const float* w_up_lora_b  = (const float*)d_in[5];
    const int*   w_down_q     = (const int*)  d_in[6];
    const float* w_down_scale = (const float*)d_in[7];
    const float* b_down       = (const float*)d_in[8];
    const float* w_down_lora_a= (const float*)d_in[9];
    const float* w_down_lora_b= (const float*)d_in[10];
    float* out = (float*)d_out;

    const int M = 8192, D = 2048, H = 8192;

    char* ws = (char*)d_ws;
    bf16* x1b = (bf16*)ws;                                   // M*D   (32 MB)
    bf16* wup = (bf16*)(ws + (size_t)M * D * 2);             // H*D   (32 MB)
    bf16* x2  = (bf16*)(ws + (size_t)M * D * 2 + (size_t)H * D * 2); // M*H (128 MB)
    bf16* wdn = x1b;  // reuse region 0 after gemm1 consumed x1b

    {
        int n4 = (M * D) / 4;
        cast_f32_to_bf16<<<dim3((n4 + 255) / 256), dim3(256), 0, stream>>>(x1, x1b, n4);
    }
    dequant_lora<<<dim3(D / 64, H / 64), dim3(256), 0, stream>>>(
        w_up_q, w_up_scale, w_up_lora_a, w_up_lora_b, wup, H, D);
    gemm_bt256<true, bf16><<<dim3(H / 256, M / 256), dim3(512), 0, stream>>>(
        x1b, wup, b_up, x2, M, H, D);
    dequant_lora<<<dim3(H / 64, D / 64), dim3(256), 0, stream>>>(
        w_down_q, w_down_scale, w_down_lora_a, w_down_lora_b, wdn, D, H);
    gemm_bt256<false, float><<<dim3(D / 256, M / 256), dim3(512), 0, stream>>>(
        x2, wdn, b_down, out, M, D, H);
}

// Round 4
// 757.649 us; speedup vs baseline: 3.1212x; 3.1212x over previous
//
#include <hip/hip_runtime.h>
#include <hip/hip_bf16.h>
#include <stdint.h>
#include <stddef.h>

typedef __bf16 bf16;
typedef bf16  bf16x4 __attribute__((ext_vector_type(4)));
typedef bf16  bf16x8 __attribute__((ext_vector_type(8)));
typedef float f32x4  __attribute__((ext_vector_type(4)));

// ---------------------------------------------------------------------------
// async global->LDS, 16B per lane. LDS dest is wave-uniform base + lane*16.
// ---------------------------------------------------------------------------
__device__ __forceinline__ void async_copy16(bf16* lds, const bf16* g) {
    __builtin_amdgcn_global_load_lds(
        (const __attribute__((address_space(1))) void*)g,
        (__attribute__((address_space(3))) void*)lds,
        16, 0, 0);
}

__device__ __forceinline__ void bar() { __builtin_amdgcn_s_barrier(); }
#define SFENCE() __builtin_amdgcn_sched_barrier(0)
#define WAIT_VM6()   do { asm volatile("s_waitcnt vmcnt(6)");   SFENCE(); } while (0)
#define WAIT_VM0()   do { asm volatile("s_waitcnt vmcnt(0)");   SFENCE(); } while (0)

// ---------------------------------------------------------------------------
// cast fp32 -> bf16, 4 elems/thread (unchanged)
// ---------------------------------------------------------------------------
__global__ __launch_bounds__(256) void cast_f32_to_bf16(
        const float* __restrict__ in, bf16* __restrict__ out, int n4) {
    int i = blockIdx.x * blockDim.x + threadIdx.x;
    if (i >= n4) return;
    const float4 v = *(const float4*)(in + (size_t)i * 4);
    bf16x4 o;
    o[0] = (bf16)v.x; o[1] = (bf16)v.y; o[2] = (bf16)v.z; o[3] = (bf16)v.w;
    *(bf16x4*)(out + (size_t)i * 4) = o;
}

// ---------------------------------------------------------------------------
// W_eff[n][k] = (q[n][k] - 7.5) * scale[n][k/64] + sum_r A[k][r]*Bm[r][n]
// (unchanged)
// ---------------------------------------------------------------------------
__global__ __launch_bounds__(256) void dequant_lora(
        const int*   __restrict__ q,
        const float* __restrict__ scale,
        const float* __restrict__ A,
        const float* __restrict__ Bm,
        bf16* __restrict__ out,
        int N, int K) {
    const int tid = threadIdx.x;
    const int k0 = blockIdx.x * 64;
    const int n0 = blockIdx.y * 64;
    const int kk = k0 + (tid & 15) * 4;
    const int nb = n0 + (tid >> 4) * 4;

    f32x4 Ar[4][4];
    #pragma unroll
    for (int i = 0; i < 4; ++i)
        #pragma unroll
        for (int rq = 0; rq < 4; ++rq)
            Ar[i][rq] = *(const f32x4*)&A[(size_t)(kk + i) * 16 + rq * 4];
    f32x4 Br[16];
    #pragma unroll
    for (int r = 0; r < 16; ++r)
        Br[r] = *(const f32x4*)&Bm[(size_t)r * N + nb];

    const int scol = (unsigned)k0 >> 6;
    #pragma unroll
    for (int nn = 0; nn < 4; ++nn) {
        const int n = nb + nn;
        const int4 qv = *(const int4*)&q[(size_t)n * K + kk];
        const float s = scale[(size_t)n * (K >> 6) + scol];
        float l0 = 0.f, l1 = 0.f, l2 = 0.f, l3 = 0.f;
        #pragma unroll
        for (int r = 0; r < 16; ++r) {
            const float bv = Br[r][nn];
            l0 += Ar[0][r >> 2][r & 3] * bv;
            l1 += Ar[1][r >> 2][r & 3] * bv;
            l2 += Ar[2][r >> 2][r & 3] * bv;
            l3 += Ar[3][r >> 2][r & 3] * bv;
        }
        bf16x4 o;
        o[0] = (bf16)(((float)qv.x - 7.5f) * s + l0);
        o[1] = (bf16)(((float)qv.y - 7.5f) * s + l1);
        o[2] = (bf16)(((float)qv.z - 7.5f) * s + l2);
        o[3] = (bf16)(((float)qv.w - 7.5f) * s + l3);
        *(bf16x4*)&out[(size_t)n * K + kk] = o;
    }
}

// ---------------------------------------------------------------------------
// gemm_bt256 v8: v6's exact schedule & register budget; ONLY changes:
//  (1) LDS split into 4 distinct __shared__ arrays + K-loop unrolled x2 so
//      the double-buffer choice is compile-time. Tests the round-2 theory:
//      with runtime dbuf index, SIInsertWaitcnts cannot prove ds_reads
//      disjoint from pending global_load_lds DMAs and attaches a
//      vmcnt-drain to every phase's read burst.
//  (2) No explicit lgkmcnt(0) before MFMA clusters — compiler emits precise
//      counted lgkm waits for plain LDS loads (early MFMAs overlap late
//      ds_reads). Fragments = v6's fa[4][2]+fb[4][2] (64 VGPR) + 128 AGPR
//      acc = 244 <= 256/wave @ 2 waves/SIMD. v7's fan[2] banking (+64 VGPR
//      -> 296 > 256) caused the scratch-spill blowup (WRITE_SIZE 0.3->2.2GB).
//
// Schedule per K-tile t (cur = parity-t arrays, nxt = other):
//  p1: read fa(m0-3)+fb(all 8) cur ; stage A-hi(t+1)->nxt | bar | MFMA Q0 | bar
//  p2: stage B-lo(t+2)->cur                               | bar | MFMA Q1 | bar
//  p3: read fa(m4-7) cur ; stage B-hi(t+2)->cur           | bar | MFMA Q2 | bar
//  p4: stage A-lo(t+2)->cur ; vmcnt(6)                    | bar | MFMA Q3 | bar
// vmcnt(6) at p4: pending = {A-hi(t+1),B-lo(t+2),B-hi(t+2),A-lo(t+2)}x2 = 8;
// retiring oldest 2 = A-hi(t+1) -> ALL of tile t+1 resident; 6 loads stay in
// flight ACROSS barriers. Tail (t+2>=NT) drains vmcnt(0).
// ---------------------------------------------------------------------------
template <bool RELU, typename OUT_T>
__global__ __launch_bounds__(512, 2) void gemm_bt256(
        const bf16* __restrict__ A, const bf16* __restrict__ B,
        const float* __restrict__ bias, OUT_T* __restrict__ C,
        int M, int N, int K) {
    __shared__ __attribute__((aligned(16))) bf16 As0[2][8192];
    __shared__ __attribute__((aligned(16))) bf16 As1[2][8192];
    __shared__ __attribute__((aligned(16))) bf16 Bs0[2][8192];
    __shared__ __attribute__((aligned(16))) bf16 Bs1[2][8192];

    const int tid  = threadIdx.x;
    const int wave = tid >> 6;
    const int lane = tid & 63;
    const int wm   = wave >> 2;     // 0..1 : row half of the 256-tile
    const int wn   = wave & 3;      // 0..3 : 64-col slice
    const int bn   = blockIdx.x;
    const int bm   = blockIdx.y;

    // staging: thread covers 16B-granule tid (rows 0..63) and tid+512
    // (rows 64..127) of each [128][64] half-tile; source col granule
    // pre-swizzled with the same involution the reads apply.
    const int srow = tid >> 3;
    const int scol = ((tid & 7) ^ (srow & 7)) * 8;   // elems
    const bf16* gA = A + ((size_t)(bm * 256) + srow) * K + scol;
    const bf16* gB = B + ((size_t)(bn * 256) + srow) * K + scol;

    auto stage2 = [&](bf16* halfBase, const bf16* g) {
        bf16* l = halfBase + wave * 512;             // wave-uniform dest
        async_copy16(l, g);
        async_copy16(l + 4096, g + (size_t)64 * K);  // rows +64
    };

    const int fr  = lane & 15;
    const int kq  = lane >> 4;
    const int cg0 = ((kq    ) ^ (fr & 7)) * 8;
    const int cg1 = ((kq + 4) ^ (fr & 7)) * 8;
    const int ra  = fr * 64;
    const int rb  = (wn & 1) * 4096 + fr * 64;       // 64-col offset in B half

    f32x4 acc[8][4];
    #pragma unroll
    for (int i = 0; i < 8; ++i)
        #pragma unroll
        for (int j = 0; j < 4; ++j) {
            f32x4 z = {0.f, 0.f, 0.f, 0.f};
            acc[i][j] = z;
        }

    // prologue: 7 half-tiles; first 4 = all of tile 0 (parity-0 arrays).
    stage2(&Bs0[0][0], gB);
    stage2(&Bs0[1][0], gB + (size_t)128 * K);
    stage2(&As0[0][0], gA);
    stage2(&As0[1][0], gA + (size_t)128 * K);
    stage2(&Bs1[0][0], gB + 64);
    stage2(&Bs1[1][0], gB + (size_t)128 * K + 64);
    stage2(&As1[0][0], gA + 64);
    WAIT_VM6();                      // 14 issued, retire oldest 8 = tile 0
    bar();

    const int NT = K >> 6;
    bf16x8 fa[4][2], fb[4][2];

    for (int t0 = 0; t0 < NT; t0 += 2) {
        #pragma unroll
        for (int u = 0; u < 2; ++u) {
            const int t = t0 + u;
            bf16 (*AsC)[8192] = u ? As1 : As0;   // cur dbuf (t&1 == u)
            bf16 (*AsN)[8192] = u ? As0 : As1;   // next dbuf
            bf16 (*BsC)[8192] = u ? Bs1 : Bs0;
            const bf16* aC = &AsC[wm][0];
            const bf16* bC = &BsC[wn >> 1][0];

            // ---- phase 1: read fa(m0-3)+fb, stage A-hi(t+1) | MFMA Q0 ---
            #pragma unroll
            for (int i = 0; i < 4; ++i) {
                fa[i][0] = *(const bf16x8*)(aC + i * 1024 + ra + cg0);
                fa[i][1] = *(const bf16x8*)(aC + i * 1024 + ra + cg1);
            }
            #pragma unroll
            for (int j = 0; j < 4; ++j) {
                fb[j][0] = *(const bf16x8*)(bC + rb + j * 1024 + cg0);
                fb[j][1] = *(const bf16x8*)(bC + rb + j * 1024 + cg1);
            }
            if (t + 1 < NT)
                stage2(&AsN[1][0], gA + (size_t)128 * K + (size_t)(t + 1) * 64);
            bar();
            __builtin_amdgcn_s_setprio(1);
            #pragma unroll
            for (int ks = 0; ks < 2; ++ks)
                #pragma unroll
                for (int i = 0; i < 4; ++i)
                    #pragma unroll
                    for (int j = 0; j < 2; ++j)
                        acc[i][j] = __builtin_amdgcn_mfma_f32_16x16x32_bf16(
                            fa[i][ks], fb[j][ks], acc[i][j], 0, 0, 0);
            __builtin_amdgcn_s_setprio(0);
            bar();

            // ---- phase 2: stage B-lo(t+2) | MFMA Q1 ---------------------
            if (t + 2 < NT)
                stage2(&BsC[0][0], gB + (size_t)(t + 2) * 64);
            bar();
            __builtin_amdgcn_s_setprio(1);
            #pragma unroll
            for (int ks = 0; ks < 2; ++ks)
                #pragma unroll
                for (int i = 0; i < 4; ++i)
                    #pragma unroll
                    for (int j = 2; j < 4; ++j)
                        acc[i][j] = __builtin_amdgcn_mfma_f32_16x16x32_bf16(
                            fa[i][ks], fb[j][ks], acc[i][j], 0, 0, 0);
            __builtin_amdgcn_s_setprio(0);
            bar();

            // ---- phase 3: read fa(m4-7), stage B-hi(t+2) | MFMA Q2 ------
            #pragma unroll
            for (int i = 0; i < 4; ++i) {
                fa[i][0] = *(const bf16x8*)(aC + (i + 4) * 1024 + ra + cg0);
                fa[i][1] = *(const bf16x8*)(aC + (i + 4) * 1024 + ra + cg1);
            }
            if (t + 2 < NT)
                stage2(&BsC[1][0], gB + (size_t)128 * K + (size_t)(t + 2) * 64);
            bar();
            __builtin_amdgcn_s_setprio(1);
            #pragma unroll
            for (int ks = 0; ks < 2; ++ks)
                #pragma unroll
                for (int i = 0; i < 4; ++i)
                    #pragma unroll
                    for (int j = 2; j < 4; ++j)
                        acc[i + 4][j] = __builtin_amdgcn_mfma_f32_16x16x32_bf16(
                            fa[i][ks], fb[j][ks], acc[i + 4][j], 0, 0, 0);
            __builtin_amdgcn_s_setprio(0);
            bar();

            // ---- phase 4: stage A-lo(t+2), vmcnt(6) | MFMA Q3 -----------
            if (t + 2 < NT) {
                stage2(&AsC[0][0], gA + (size_t)(t + 2) * 64);
                WAIT_VM6();          // retires A-hi(t+1): tile t+1 resident
            } else {
                WAIT_VM0();          // tail drain
            }
            bar();
            __builtin_amdgcn_s_setprio(1);
            #pragma unroll
            for (int ks = 0; ks < 2; ++ks)
                #pragma unroll
                for (int i = 0; i < 4; ++i)
                    #pragma unroll
                    for (int j = 0; j < 2; ++j)
                        acc[i + 4][j] = __builtin_amdgcn_mfma_f32_16x16x32_bf16(
                            fa[i][ks], fb[j][ks], acc[i + 4][j], 0, 0, 0);
            __builtin_amdgcn_s_setprio(0);
            bar();
        }
    }

    // epilogue: C/D layout col = lane&15, row = (lane>>4)*4 + reg (verified)
    const int er = bm * 256 + wm * 128 + (lane >> 4) * 4;
    const int ec = bn * 256 + wn * 64 + fr;
    #pragma unroll
    for (int j = 0; j < 4; ++j) {
        const int col = ec + j * 16;
        const float bv = bias[col];
        #pragma unroll
        for (int i = 0; i < 8; ++i) {
            #pragma unroll
            for (int r = 0; r < 4; ++r) {
                const int row = er + i * 16 + r;
                float v = acc[i][j][r] + bv;
                if (RELU) v = v > 0.f ? v : 0.f;
                C[(size_t)row * N + col] = (OUT_T)v;
            }
        }
    }
}

// ---------------------------------------------------------------------------
extern "C" void kernel_launch(void* const* d_in, const int* in_sizes, int n_in,
                              void* d_out, int out_size, void* d_ws, size_t ws_size,
                              hipStream_t stream) {
    const float* x1           = (const float*)d_in[0];
    const int*   w_up_q       = (const int*)  d_in[1];
    const float* w_up_scale   = (const float*)d_in[2];
    const float* b_up         = (const float*)d_in[3];
    const float* w_up_lora_a  = (const float*)d_in[4];
    const float* w_up_lora_b  = (const float*)d_in[5];
    const int*   w_down_q     = (const int*)  d_in[6];
    const float* w_down_scale = (const float*)d_in[7];
    const float* b_down       = (const float*)d_in[8];
    const float* w_down_lora_a= (const float*)d_in[9];
    const float* w_down_lora_b= (const float*)d_in[10];
    float* out = (float*)d_out;

    const int M = 8192, D = 2048, H = 8192;

    char* ws = (char*)d_ws;
    bf16* x1b = (bf16*)ws;                                   // M*D   (32 MB)
    bf16* wup = (bf16*)(ws + (size_t)M * D * 2);             // H*D   (32 MB)
    bf16* x2  = (bf16*)(ws + (size_t)M * D * 2 + (size_t)H * D * 2); // M*H (128 MB)
    bf16* wdn = x1b;  // reuse region 0 after gemm1 consumed x1b

    {
        int n4 = (M * D) / 4;
        cast_f32_to_bf16<<<dim3((n4 + 255) / 256), dim3(256), 0, stream>>>(x1, x1b, n4);
    }
    dequant_lora<<<dim3(D / 64, H / 64), dim3(256), 0, stream>>>(
        w_up_q, w_up_scale, w_up_lora_a, w_up_lora_b, wup, H, D);
    gemm_bt256<true, bf16><<<dim3(H / 256, M / 256), dim3(512), 0, stream>>>(
        x1b, wup, b_up, x2, M, H, D);
    dequant_lora<<<dim3(H / 64, D / 64), dim3(256), 0, stream>>>(
        w_down_q, w_down_scale, w_down_lora_a, w_down_lora_b, wdn, D, H);
    gemm_bt256<false, float><<<dim3(D / 256, M / 256), dim3(512), 0, stream>>>(
        x2, wdn, b_down, out, M, D, H);
}